// Round 18
// baseline (294.386 us; speedup 1.0000x reference)
//
#include <hip/hip_runtime.h>
#include <stdint.h>
#include <stddef.h>

#define D_DIM 1024
#define T_LEN 4096
#define B_SZ 8
#define M_ROWS 32768   // B_SZ * T_LEN
#define KTOT 1024
#define CHUNK 64
#define NCHUNK 64      // T_LEN / CHUNK

typedef unsigned short u16;
typedef unsigned short u16x8 __attribute__((ext_vector_type(8)));
typedef __bf16 bf16x8 __attribute__((ext_vector_type(8)));
typedef float f32x4 __attribute__((ext_vector_type(4)));

__device__ __forceinline__ u16 f2bf(float f) {
    union { float f; unsigned u; } v; v.f = f;
    unsigned r = v.u + 0x7fffu + ((v.u >> 16) & 1u);
    return (u16)(r >> 16);
}
__device__ __forceinline__ float bf2f(u16 h) {
    union { unsigned u; float f; } v; v.u = ((unsigned)h) << 16;
    return v.f;
}

// ---------------- fused f32->bf16 conversion: x + {Wk,Wv->wcat, Wq->wqb} ----
__global__ void convert_all_kernel(const float* __restrict__ x,
                                   const float* __restrict__ Wk, const float* __restrict__ Wv,
                                   const float* __restrict__ Wq,
                                   u16* __restrict__ xb, u16* __restrict__ wcat,
                                   u16* __restrict__ wqb) {
    const int NX = (M_ROWS * D_DIM) / 4;          // x in float4 units
    const int total = NX + 3072 * 256;            // + 3072 weight rows x 256 float4
    int stride = gridDim.x * blockDim.x;
    for (int j = blockIdx.x * blockDim.x + threadIdx.x; j < total; j += stride) {
        const float4* s4;
        ushort4* d4;
        if (j < NX) {
            s4 = (const float4*)x + j;
            d4 = (ushort4*)xb + j;
        } else {
            int idx = j - NX;
            int r = idx >> 8, c4 = idx & 255;
            if (r < 2048) {
                int g = r >> 5, jj = r & 31;
                s4 = (const float4*)((jj < 16 ? Wk : Wv) + (size_t)(g * 16 + (jj & 15)) * D_DIM) + c4;
                d4 = (ushort4*)(wcat + (size_t)r * D_DIM) + c4;
            } else {
                s4 = (const float4*)(Wq + (size_t)(r - 2048) * D_DIM) + c4;
                d4 = (ushort4*)(wqb + (size_t)(r - 2048) * D_DIM) + c4;
            }
        }
        float4 v = *s4;
        ushort4 o;
        o.x = f2bf(v.x); o.y = f2bf(v.y); o.z = f2bf(v.z); o.w = f2bf(v.w);
        *d4 = o;
    }
}

// ---------------- async global->LDS, 16B per lane ----------------
__device__ __forceinline__ void gload16(const u16* g, u16* l) {
    __builtin_amdgcn_global_load_lds(
        (const __attribute__((address_space(1))) void*)g,
        (__attribute__((address_space(3))) void*)l,
        16, 0, 0);
}

// ---------------- r8-structure GEMM + setprio around MFMA clusters ----------
// K-loop: BM=BN=256, BK=64, 8 waves (2Mx4N), wave 128x64, LDS 2x64KB dbuf,
// 4 phases/K-tile, compiler-scheduled lgkm, counted vmcnt(2)+barrier at p1/p3.
// T5: s_setprio(1) around each 16-MFMA quad (A/B vs r17: cat was 143.7).
// CAT epilogue: u-tile -> XOR-swizzled LDS, coalesced u16x8 stores + fused
// per-chunk carry. Single epilogue: direct stores (measured best).
template<bool CAT>
__global__ __launch_bounds__(512, 2) void gemm17_kernel(
    const u16* __restrict__ A,
    const u16* __restrict__ Bg,
    const float* __restrict__ bias0,
    const float* __restrict__ bias1,
    u16* __restrict__ Uout,
    float* __restrict__ Fout,
    const float* __restrict__ decay,
    float* __restrict__ localc)
{
    constexpr int NT = KTOT / 64;      // 16 K-tiles
    __shared__ u16 smem[2 * 32768];    // 128 KB

    const int tid  = threadIdx.x;
    const int w    = tid >> 6;
    const int lane = tid & 63;

    const int cpx = gridDim.x >> 3;
    const int swz = (blockIdx.x & 7) * cpx + (blockIdx.x >> 3);
    const int nCol = CAT ? 8 : 4;
    const int M0 = (swz / nCol) * 256;
    const int N0 = (swz % nCol) * 256;

    const int srow = lane >> 2;
    const int sg   = (lane & 3) ^ ((srow >> 1) & 3);

    const u16* pA0 = A  + (size_t)(M0 + w * 32 +      srow) * KTOT + sg * 8;
    const u16* pA1 = A  + (size_t)(M0 + w * 32 + 16 + srow) * KTOT + sg * 8;
    const u16* pB0 = Bg + (size_t)(N0 + w * 32 +      srow) * KTOT + sg * 8;
    const u16* pB1 = Bg + (size_t)(N0 + w * 32 + 16 + srow) * KTOT + sg * 8;

    auto stA = [&](u16* nxt, int h) {
        gload16(pA0, nxt + h * 8192 + w * 1024);       pA0 += 32;
        gload16(pA1, nxt + h * 8192 + w * 1024 + 512); pA1 += 32;
    };
    auto stB = [&](u16* nxt, int h) {
        gload16(pB0, nxt + 16384 + h * 8192 + w * 1024);       pB0 += 32;
        gload16(pB1, nxt + 16384 + h * 8192 + w * 1024 + 512); pB1 += 32;
    };

    const int wrow = (w >> 2) * 128;
    const int wcol = (w & 3) * 64;
    const int fr = lane & 15;
    const int fq = lane >> 4;

    int offA[8], offB[4];
#pragma unroll
    for (int m = 0; m < 8; ++m) {
        int row = wrow + m * 16 + fr;
        offA[m] = row * 32 + ((fq ^ ((row >> 1) & 3)) << 3);
    }
#pragma unroll
    for (int n = 0; n < 4; ++n) {
        int row = wcol + n * 16 + fr;
        offB[n] = 16384 + row * 32 + ((fq ^ ((row >> 1) & 3)) << 3);
    }

    f32x4 acc[8][4] = {};
    bf16x8 aA[4], aB[4], aC[4], aD[4], bA[4], bC[4];

    stA(smem, 0); stB(smem, 0); stA(smem, 1); stB(smem, 1);
    asm volatile("s_waitcnt vmcnt(4)" ::: "memory");
    __builtin_amdgcn_s_barrier();
#pragma unroll
    for (int m = 0; m < 4; ++m) aA[m] = *(const bf16x8*)(smem + offA[m]);
#pragma unroll
    for (int n = 0; n < 4; ++n) bA[n] = *(const bf16x8*)(smem + offB[n]);

#pragma unroll 1
    for (int t = 0; t < NT; ++t) {
        const u16* cur = smem + (t & 1) * 32768;
        u16* nxt = smem + ((t + 1) & 1) * 32768;
        const bool pf = (t + 1 < NT);

        // ===== p0: read aB + stage A-ks0(t+1) + MFMA Q0 =====
#pragma unroll
        for (int m = 0; m < 4; ++m) aB[m] = *(const bf16x8*)(cur + offA[4 + m]);
        if (pf) stA(nxt, 0);
        __builtin_amdgcn_s_setprio(1);
#pragma unroll
        for (int m = 0; m < 4; ++m)
#pragma unroll
            for (int n = 0; n < 4; ++n)
                acc[m][n] = __builtin_amdgcn_mfma_f32_16x16x32_bf16(aA[m], bA[n], acc[m][n], 0, 0, 0);
        __builtin_amdgcn_s_setprio(0);

        // ===== p1: vmcnt(2) retires tile-t ks1; BAR; read aC,bC + stage + MFMA Q1 =====
        if (pf) { asm volatile("s_waitcnt vmcnt(2)" ::: "memory"); }
        else    { asm volatile("s_waitcnt vmcnt(0)" ::: "memory"); }
        __builtin_amdgcn_s_barrier();
#pragma unroll
        for (int m = 0; m < 4; ++m) aC[m] = *(const bf16x8*)(cur + 8192 + offA[m]);
#pragma unroll
        for (int n = 0; n < 4; ++n) bC[n] = *(const bf16x8*)(cur + 8192 + offB[n]);
        if (pf) stB(nxt, 0);
        __builtin_amdgcn_s_setprio(1);
#pragma unroll
        for (int m = 0; m < 4; ++m)
#pragma unroll
            for (int n = 0; n < 4; ++n)
                acc[4 + m][n] = __builtin_amdgcn_mfma_f32_16x16x32_bf16(aB[m], bA[n], acc[4 + m][n], 0, 0, 0);
        __builtin_amdgcn_s_setprio(0);

        // ===== p2: read aD + stage A-ks1(t+1) + MFMA Q2 =====
#pragma unroll
        for (int m = 0; m < 4; ++m) aD[m] = *(const bf16x8*)(cur + 8192 + offA[4 + m]);
        if (pf) stA(nxt, 1);
        __builtin_amdgcn_s_setprio(1);
#pragma unroll
        for (int m = 0; m < 4; ++m)
#pragma unroll
            for (int n = 0; n < 4; ++n)
                acc[m][n] = __builtin_amdgcn_mfma_f32_16x16x32_bf16(aC[m], bC[n], acc[m][n], 0, 0, 0);
        __builtin_amdgcn_s_setprio(0);

        // ===== p3: vmcnt(2) retires tile-(t+1) ks0; BAR; read next aA,bA + stage + MFMA Q3 =====
        if (pf) { asm volatile("s_waitcnt vmcnt(2)" ::: "memory"); }
        __builtin_amdgcn_s_barrier();
        if (pf) {
#pragma unroll
            for (int m = 0; m < 4; ++m) aA[m] = *(const bf16x8*)(nxt + offA[m]);
#pragma unroll
            for (int n = 0; n < 4; ++n) bA[n] = *(const bf16x8*)(nxt + offB[n]);
            stB(nxt, 1);
        }
        __builtin_amdgcn_s_setprio(1);
#pragma unroll
        for (int m = 0; m < 4; ++m)
#pragma unroll
            for (int n = 0; n < 4; ++n)
                acc[4 + m][n] = __builtin_amdgcn_mfma_f32_16x16x32_bf16(aD[m], bC[n], acc[4 + m][n], 0, 0, 0);
        __builtin_amdgcn_s_setprio(0);
    }

    // epilogue (C/D layout: col=lane&15, row=(lane>>4)*4+reg)
    if (CAT) {
        asm volatile("s_waitcnt lgkmcnt(0) vmcnt(0)" ::: "memory");
        __syncthreads();   // all waves done; smem free
        u16 (*uld)[128] = (u16(*)[128])smem;
        const int ucol0 = N0 / 2;
#pragma unroll
        for (int m = 0; m < 8; ++m) {
#pragma unroll
            for (int p = 0; p < 2; ++p) {
                int lcol = (w & 3) * 32 + p * 16 + fr;
                float b0 = bias0[ucol0 + lcol];
                float b1 = bias1[ucol0 + lcol];
#pragma unroll
                for (int j = 0; j < 4; ++j) {
                    int row = wrow + m * 16 + fq * 4 + j;
                    float kl = acc[m][2 * p][j] + b0;
                    float vv = acc[m][2 * p + 1][j] + b1;
                    float sig = 1.0f / (1.0f + __expf(-kl));
                    uld[row][lcol ^ (((row >> 2) & 3) << 4)] = f2bf(sig * vv);
                }
            }
        }
        __syncthreads();
#pragma unroll
        for (int g = 0; g < 8; ++g) {
            int idx = tid + g * 512;
            int row = idx >> 4, grp = idx & 15;
            int lcol = (grp * 8) ^ (((row >> 2) & 3) << 4);
            *(u16x8*)(Uout + (size_t)(M0 + row) * D_DIM + ucol0 + grp * 8) =
                *(const u16x8*)&uld[row][lcol];
        }
        {
            int chunk = tid >> 7;
            int col   = tid & 127;
            float dec = decay[ucol0 + col];
            float carry = 0.f;
#pragma unroll 4
            for (int s = 0; s < 64; ++s) {
                int r = chunk * 64 + s;
                carry = fmaf(carry, dec, bf2f(uld[r][col ^ (((r >> 2) & 3) << 4)]));
            }
            localc[(size_t)(M0 / 64 + chunk) * D_DIM + ucol0 + col] = carry;
        }
    } else {
#pragma unroll
        for (int n = 0; n < 4; ++n) {
            int col = N0 + wcol + n * 16 + fr;
            float b0 = bias0[col];
            float b1 = bias1[col];
#pragma unroll
            for (int m = 0; m < 8; ++m) {
                int row0 = M0 + wrow + m * 16 + fq * 4;
#pragma unroll
                for (int j = 0; j < 4; ++j)
                    Fout[(size_t)(row0 + j) * D_DIM + col] = (acc[m][n][j] + b0) / b1;
            }
        }
    }
}

// ---------------- scan pass B: PARALLEL pair-scan over chunk carries --------
// Pair (v,g): op(left,right) = (right.v + left.v*right.g, left.g*right.g).
// Block = (b, dgroup of 16 d): 1024 threads = 64 chunks x 16 d. Hillis-Steele
// 6 steps in LDS. prefix[c] = c==0 ? P0 : P0*G_{c-1}+V_{c-1}; final from c=63.
__global__ __launch_bounds__(1024) void carry_scan_kernel(
    const float* __restrict__ localc, const float* __restrict__ state_p,
    const float* __restrict__ decay, float* __restrict__ prefix,
    float* __restrict__ final_p)
{
    __shared__ float Vs[64][17], Gs[64][17];
    const int tid = threadIdx.x;
    const int c  = tid >> 4;
    const int dl = tid & 15;
    const int b  = blockIdx.x >> 6;    // 8 batches
    const int dg = blockIdx.x & 63;    // 64 d-groups of 16
    const int d  = dg * 16 + dl;

    float dec = decay[d];
    float g = dec;
#pragma unroll
    for (int i = 0; i < 6; ++i) g *= g;     // dec^64
    float v = localc[(size_t)(b * NCHUNK + c) * D_DIM + d];
    Vs[c][dl] = v; Gs[c][dl] = g;
    __syncthreads();
#pragma unroll
    for (int s = 1; s < 64; s <<= 1) {
        float lv = 0.f, lg = 1.f;
        if (c >= s) { lv = Vs[c - s][dl]; lg = Gs[c - s][dl]; }
        __syncthreads();
        if (c >= s) {
            float sv = Vs[c][dl], sgg = Gs[c][dl];
            Vs[c][dl] = fmaf(lv, sgg, sv);
            Gs[c][dl] = lg * sgg;
        }
        __syncthreads();
    }
    float P0 = state_p[b * D_DIM + d];
    float pref = (c == 0) ? P0 : fmaf(P0, Gs[c - 1][dl], Vs[c - 1][dl]);
    prefix[(size_t)(b * NCHUNK + c) * D_DIM + d] = pref;
    if (c == 63)
        final_p[b * D_DIM + d] = fmaf(P0, Gs[63][dl], Vs[63][dl]);
}

// ---------------- scan pass C: reconstruct p in place (x8 vectorized) ----------------
__global__ void reconstruct_kernel(u16* __restrict__ u, const float* __restrict__ decay,
                                   const float* __restrict__ prefix) {
    int id = blockIdx.x * blockDim.x + threadIdx.x;   // 65536
    int d8 = id & 127;
    int c  = (id >> 7) & (NCHUNK - 1);
    int b  = id >> 13;
    float4 dlo = ((const float4*)decay)[d8 * 2];
    float4 dhi = ((const float4*)decay)[d8 * 2 + 1];
    float dec[8] = {dlo.x, dlo.y, dlo.z, dlo.w, dhi.x, dhi.y, dhi.z, dhi.w};
    const float* pf = prefix + ((size_t)(b * NCHUNK + c)) * D_DIM + d8 * 8;
    float p[8];
#pragma unroll
    for (int j = 0; j < 8; ++j) p[j] = pf[j];
    u16* up = u + ((size_t)b * T_LEN + (size_t)c * CHUNK) * D_DIM + d8 * 8;
    for (int s = 0; s < CHUNK; ++s) {
        u16x8 v = *(const u16x8*)(up + (size_t)s * D_DIM);
        u16x8 o;
#pragma unroll
        for (int j = 0; j < 8; ++j) {
            p[j] = fmaf(p[j], dec[j], bf2f(v[j]));
            o[j] = f2bf(p[j]);
        }
        *(u16x8*)(up + (size_t)s * D_DIM) = o;
    }
}

extern "C" void kernel_launch(void* const* d_in, const int* in_sizes, int n_in,
                              void* d_out, int out_size, void* d_ws, size_t ws_size,
                              hipStream_t stream) {
    const float* x       = (const float*)d_in[0];
    const float* state_p = (const float*)d_in[1];
    const float* decay   = (const float*)d_in[2];
    const float* mass    = (const float*)d_in[3];
    const float* Wq      = (const float*)d_in[4];
    const float* bq      = (const float*)d_in[5];
    const float* Wk      = (const float*)d_in[6];
    const float* bk      = (const float*)d_in[7];
    const float* Wv      = (const float*)d_in[8];
    const float* bv      = (const float*)d_in[9];

    float* out     = (float*)d_out;
    float* final_p = out + (size_t)M_ROWS * D_DIM;

    // x_bf16 staged in d_out's first 64MB (dead before final GEMM overwrites it)
    u16* xb = (u16*)d_out;

    // workspace layout (~74MB)
    u16* wcat = (u16*)d_ws;                          // [2048][1024] interleaved Wk/Wv
    u16* wqb  = wcat + 2048 * 1024;
    u16* ub   = wqb + 1024 * 1024;                   // u then p in place, 64MB
    float* localc = (float*)(ub + (size_t)M_ROWS * D_DIM);
    float* prefix = localc + B_SZ * NCHUNK * D_DIM;

    convert_all_kernel<<<4096, 256, 0, stream>>>(x, Wk, Wv, Wq, xb, wcat, wqb);

    // u = sigmoid(x Wk^T + bk) * (x Wv^T + bv); also emits localc (fused carry)
    gemm17_kernel<true><<<dim3(1024), dim3(512), 0, stream>>>(
        xb, wcat, bk, bv, ub, nullptr, decay, localc);

    carry_scan_kernel<<<512, 1024, 0, stream>>>(localc, state_p, decay, prefix, final_p);
    reconstruct_kernel<<<256, 256, 0, stream>>>(ub, decay, prefix);

    // velocities = (p Wq^T + bq) / mass
    gemm17_kernel<false><<<dim3(512), dim3(512), 0, stream>>>(
        ub, wqb, bq, mass, nullptr, out, nullptr, nullptr);
}

// Round 19
// 292.046 us; speedup vs baseline: 1.0080x; 1.0080x over previous
//
#include <hip/hip_runtime.h>
#include <stdint.h>
#include <stddef.h>

#define D_DIM 1024
#define T_LEN 4096
#define B_SZ 8
#define M_ROWS 32768   // B_SZ * T_LEN
#define KTOT 1024
#define CHUNK 64
#define NCHUNK 64      // T_LEN / CHUNK

typedef unsigned short u16;
typedef unsigned short u16x8 __attribute__((ext_vector_type(8)));
typedef __bf16 bf16x8 __attribute__((ext_vector_type(8)));
typedef float f32x4 __attribute__((ext_vector_type(4)));

__device__ __forceinline__ u16 f2bf(float f) {
    union { float f; unsigned u; } v; v.f = f;
    unsigned r = v.u + 0x7fffu + ((v.u >> 16) & 1u);
    return (u16)(r >> 16);
}
__device__ __forceinline__ float bf2f(u16 h) {
    union { unsigned u; float f; } v; v.u = ((unsigned)h) << 16;
    return v.f;
}

// ---------------- fused f32->bf16 conversion: x + {Wk,Wv->wcat, Wq->wqb} ----
__global__ void convert_all_kernel(const float* __restrict__ x,
                                   const float* __restrict__ Wk, const float* __restrict__ Wv,
                                   const float* __restrict__ Wq,
                                   u16* __restrict__ xb, u16* __restrict__ wcat,
                                   u16* __restrict__ wqb) {
    const int NX = (M_ROWS * D_DIM) / 4;          // x in float4 units
    const int total = NX + 3072 * 256;            // + 3072 weight rows x 256 float4
    int stride = gridDim.x * blockDim.x;
    for (int j = blockIdx.x * blockDim.x + threadIdx.x; j < total; j += stride) {
        const float4* s4;
        ushort4* d4;
        if (j < NX) {
            s4 = (const float4*)x + j;
            d4 = (ushort4*)xb + j;
        } else {
            int idx = j - NX;
            int r = idx >> 8, c4 = idx & 255;
            if (r < 2048) {
                int g = r >> 5, jj = r & 31;
                s4 = (const float4*)((jj < 16 ? Wk : Wv) + (size_t)(g * 16 + (jj & 15)) * D_DIM) + c4;
                d4 = (ushort4*)(wcat + (size_t)r * D_DIM) + c4;
            } else {
                s4 = (const float4*)(Wq + (size_t)(r - 2048) * D_DIM) + c4;
                d4 = (ushort4*)(wqb + (size_t)(r - 2048) * D_DIM) + c4;
            }
        }
        float4 v = *s4;
        ushort4 o;
        o.x = f2bf(v.x); o.y = f2bf(v.y); o.z = f2bf(v.z); o.w = f2bf(v.w);
        *d4 = o;
    }
}

// ---------------- async global->LDS, 16B per lane ----------------
__device__ __forceinline__ void gload16(const u16* g, u16* l) {
    __builtin_amdgcn_global_load_lds(
        (const __attribute__((address_space(1))) void*)g,
        (__attribute__((address_space(3))) void*)l,
        16, 0, 0);
}

// ---------------- best-measured GEMM (r17 structure, no setprio) ------------
// K-loop: BM=BN=256, BK=64, 8 waves (2Mx4N), wave 128x64, LDS 2x64KB dbuf,
// 4 phases/K-tile, compiler-scheduled lgkm, counted vmcnt(2)+barrier at p1/p3.
// CAT epilogue: u-tile -> XOR-swizzled LDS, coalesced u16x8 stores + fused
// per-chunk carry. Single epilogue: direct stores (measured best).
template<bool CAT>
__global__ __launch_bounds__(512, 2) void gemm18_kernel(
    const u16* __restrict__ A,
    const u16* __restrict__ Bg,
    const float* __restrict__ bias0,
    const float* __restrict__ bias1,
    u16* __restrict__ Uout,
    float* __restrict__ Fout,
    const float* __restrict__ decay,
    float* __restrict__ localc)
{
    constexpr int NT = KTOT / 64;      // 16 K-tiles
    __shared__ u16 smem[2 * 32768];    // 128 KB

    const int tid  = threadIdx.x;
    const int w    = tid >> 6;
    const int lane = tid & 63;

    const int cpx = gridDim.x >> 3;
    const int swz = (blockIdx.x & 7) * cpx + (blockIdx.x >> 3);
    const int nCol = CAT ? 8 : 4;
    const int M0 = (swz / nCol) * 256;
    const int N0 = (swz % nCol) * 256;

    const int srow = lane >> 2;
    const int sg   = (lane & 3) ^ ((srow >> 1) & 3);

    const u16* pA0 = A  + (size_t)(M0 + w * 32 +      srow) * KTOT + sg * 8;
    const u16* pA1 = A  + (size_t)(M0 + w * 32 + 16 + srow) * KTOT + sg * 8;
    const u16* pB0 = Bg + (size_t)(N0 + w * 32 +      srow) * KTOT + sg * 8;
    const u16* pB1 = Bg + (size_t)(N0 + w * 32 + 16 + srow) * KTOT + sg * 8;

    auto stA = [&](u16* nxt, int h) {
        gload16(pA0, nxt + h * 8192 + w * 1024);       pA0 += 32;
        gload16(pA1, nxt + h * 8192 + w * 1024 + 512); pA1 += 32;
    };
    auto stB = [&](u16* nxt, int h) {
        gload16(pB0, nxt + 16384 + h * 8192 + w * 1024);       pB0 += 32;
        gload16(pB1, nxt + 16384 + h * 8192 + w * 1024 + 512); pB1 += 32;
    };

    const int wrow = (w >> 2) * 128;
    const int wcol = (w & 3) * 64;
    const int fr = lane & 15;
    const int fq = lane >> 4;

    int offA[8], offB[4];
#pragma unroll
    for (int m = 0; m < 8; ++m) {
        int row = wrow + m * 16 + fr;
        offA[m] = row * 32 + ((fq ^ ((row >> 1) & 3)) << 3);
    }
#pragma unroll
    for (int n = 0; n < 4; ++n) {
        int row = wcol + n * 16 + fr;
        offB[n] = 16384 + row * 32 + ((fq ^ ((row >> 1) & 3)) << 3);
    }

    f32x4 acc[8][4] = {};
    bf16x8 aA[4], aB[4], aC[4], aD[4], bA[4], bC[4];

    stA(smem, 0); stB(smem, 0); stA(smem, 1); stB(smem, 1);
    asm volatile("s_waitcnt vmcnt(4)" ::: "memory");
    __builtin_amdgcn_s_barrier();
#pragma unroll
    for (int m = 0; m < 4; ++m) aA[m] = *(const bf16x8*)(smem + offA[m]);
#pragma unroll
    for (int n = 0; n < 4; ++n) bA[n] = *(const bf16x8*)(smem + offB[n]);

#pragma unroll 1
    for (int t = 0; t < NT; ++t) {
        const u16* cur = smem + (t & 1) * 32768;
        u16* nxt = smem + ((t + 1) & 1) * 32768;
        const bool pf = (t + 1 < NT);

        // ===== p0: read aB + stage A-ks0(t+1) + MFMA Q0 =====
#pragma unroll
        for (int m = 0; m < 4; ++m) aB[m] = *(const bf16x8*)(cur + offA[4 + m]);
        if (pf) stA(nxt, 0);
#pragma unroll
        for (int m = 0; m < 4; ++m)
#pragma unroll
            for (int n = 0; n < 4; ++n)
                acc[m][n] = __builtin_amdgcn_mfma_f32_16x16x32_bf16(aA[m], bA[n], acc[m][n], 0, 0, 0);

        // ===== p1: vmcnt(2) retires tile-t ks1; BAR; read aC,bC + stage + MFMA Q1 =====
        if (pf) { asm volatile("s_waitcnt vmcnt(2)" ::: "memory"); }
        else    { asm volatile("s_waitcnt vmcnt(0)" ::: "memory"); }
        __builtin_amdgcn_s_barrier();
#pragma unroll
        for (int m = 0; m < 4; ++m) aC[m] = *(const bf16x8*)(cur + 8192 + offA[m]);
#pragma unroll
        for (int n = 0; n < 4; ++n) bC[n] = *(const bf16x8*)(cur + 8192 + offB[n]);
        if (pf) stB(nxt, 0);
#pragma unroll
        for (int m = 0; m < 4; ++m)
#pragma unroll
            for (int n = 0; n < 4; ++n)
                acc[4 + m][n] = __builtin_amdgcn_mfma_f32_16x16x32_bf16(aB[m], bA[n], acc[4 + m][n], 0, 0, 0);

        // ===== p2: read aD + stage A-ks1(t+1) + MFMA Q2 =====
#pragma unroll
        for (int m = 0; m < 4; ++m) aD[m] = *(const bf16x8*)(cur + 8192 + offA[4 + m]);
        if (pf) stA(nxt, 1);
#pragma unroll
        for (int m = 0; m < 4; ++m)
#pragma unroll
            for (int n = 0; n < 4; ++n)
                acc[m][n] = __builtin_amdgcn_mfma_f32_16x16x32_bf16(aC[m], bC[n], acc[m][n], 0, 0, 0);

        // ===== p3: vmcnt(2) retires tile-(t+1) ks0; BAR; read next aA,bA + stage + MFMA Q3 =====
        if (pf) { asm volatile("s_waitcnt vmcnt(2)" ::: "memory"); }
        __builtin_amdgcn_s_barrier();
        if (pf) {
#pragma unroll
            for (int m = 0; m < 4; ++m) aA[m] = *(const bf16x8*)(nxt + offA[m]);
#pragma unroll
            for (int n = 0; n < 4; ++n) bA[n] = *(const bf16x8*)(nxt + offB[n]);
            stB(nxt, 1);
        }
#pragma unroll
        for (int m = 0; m < 4; ++m)
#pragma unroll
            for (int n = 0; n < 4; ++n)
                acc[4 + m][n] = __builtin_amdgcn_mfma_f32_16x16x32_bf16(aD[m], bC[n], acc[4 + m][n], 0, 0, 0);
    }

    // epilogue (C/D layout: col=lane&15, row=(lane>>4)*4+reg)
    if (CAT) {
        asm volatile("s_waitcnt lgkmcnt(0) vmcnt(0)" ::: "memory");
        __syncthreads();   // all waves done; smem free
        u16 (*uld)[128] = (u16(*)[128])smem;
        const int ucol0 = N0 / 2;
#pragma unroll
        for (int m = 0; m < 8; ++m) {
#pragma unroll
            for (int p = 0; p < 2; ++p) {
                int lcol = (w & 3) * 32 + p * 16 + fr;
                float b0 = bias0[ucol0 + lcol];
                float b1 = bias1[ucol0 + lcol];
#pragma unroll
                for (int j = 0; j < 4; ++j) {
                    int row = wrow + m * 16 + fq * 4 + j;
                    float kl = acc[m][2 * p][j] + b0;
                    float vv = acc[m][2 * p + 1][j] + b1;
                    float sig = 1.0f / (1.0f + __expf(-kl));
                    uld[row][lcol ^ (((row >> 2) & 3) << 4)] = f2bf(sig * vv);
                }
            }
        }
        __syncthreads();
#pragma unroll
        for (int g = 0; g < 8; ++g) {
            int idx = tid + g * 512;
            int row = idx >> 4, grp = idx & 15;
            int lcol = (grp * 8) ^ (((row >> 2) & 3) << 4);
            *(u16x8*)(Uout + (size_t)(M0 + row) * D_DIM + ucol0 + grp * 8) =
                *(const u16x8*)&uld[row][lcol];
        }
        {
            int chunk = tid >> 7;
            int col   = tid & 127;
            float dec = decay[ucol0 + col];
            float carry = 0.f;
#pragma unroll 4
            for (int s = 0; s < 64; ++s) {
                int r = chunk * 64 + s;
                carry = fmaf(carry, dec, bf2f(uld[r][col ^ (((r >> 2) & 3) << 4)]));
            }
            localc[(size_t)(M0 / 64 + chunk) * D_DIM + ucol0 + col] = carry;
        }
    } else {
#pragma unroll
        for (int n = 0; n < 4; ++n) {
            int col = N0 + wcol + n * 16 + fr;
            float b0 = bias0[col];
            float b1 = bias1[col];
#pragma unroll
            for (int m = 0; m < 8; ++m) {
                int row0 = M0 + wrow + m * 16 + fq * 4;
#pragma unroll
                for (int j = 0; j < 4; ++j)
                    Fout[(size_t)(row0 + j) * D_DIM + col] = (acc[m][n][j] + b0) / b1;
            }
        }
    }
}

// ---------------- scan pass B: PARALLEL pair-scan over chunk carries --------
// Pair (v,g): op(left,right) = (right.v + left.v*right.g, left.g*right.g).
// Block = (b, dgroup of 16 d): 1024 threads = 64 chunks x 16 d. Hillis-Steele
// 6 steps in LDS. prefix[c] = c==0 ? P0 : P0*G_{c-1}+V_{c-1}; final from c=63.
__global__ __launch_bounds__(1024) void carry_scan_kernel(
    const float* __restrict__ localc, const float* __restrict__ state_p,
    const float* __restrict__ decay, float* __restrict__ prefix,
    float* __restrict__ final_p)
{
    __shared__ float Vs[64][17], Gs[64][17];
    const int tid = threadIdx.x;
    const int c  = tid >> 4;
    const int dl = tid & 15;
    const int b  = blockIdx.x >> 6;    // 8 batches
    const int dg = blockIdx.x & 63;    // 64 d-groups of 16
    const int d  = dg * 16 + dl;

    float dec = decay[d];
    float g = dec;
#pragma unroll
    for (int i = 0; i < 6; ++i) g *= g;     // dec^64
    float v = localc[(size_t)(b * NCHUNK + c) * D_DIM + d];
    Vs[c][dl] = v; Gs[c][dl] = g;
    __syncthreads();
#pragma unroll
    for (int s = 1; s < 64; s <<= 1) {
        float lv = 0.f, lg = 1.f;
        if (c >= s) { lv = Vs[c - s][dl]; lg = Gs[c - s][dl]; }
        __syncthreads();
        if (c >= s) {
            float sv = Vs[c][dl], sgg = Gs[c][dl];
            Vs[c][dl] = fmaf(lv, sgg, sv);
            Gs[c][dl] = lg * sgg;
        }
        __syncthreads();
    }
    float P0 = state_p[b * D_DIM + d];
    float pref = (c == 0) ? P0 : fmaf(P0, Gs[c - 1][dl], Vs[c - 1][dl]);
    prefix[(size_t)(b * NCHUNK + c) * D_DIM + d] = pref;
    if (c == 63)
        final_p[b * D_DIM + d] = fmaf(P0, Gs[63][dl], Vs[63][dl]);
}

// ---------------- scan pass C: reconstruct p in place (x8 vectorized) ----------------
__global__ void reconstruct_kernel(u16* __restrict__ u, const float* __restrict__ decay,
                                   const float* __restrict__ prefix) {
    int id = blockIdx.x * blockDim.x + threadIdx.x;   // 65536
    int d8 = id & 127;
    int c  = (id >> 7) & (NCHUNK - 1);
    int b  = id >> 13;
    float4 dlo = ((const float4*)decay)[d8 * 2];
    float4 dhi = ((const float4*)decay)[d8 * 2 + 1];
    float dec[8] = {dlo.x, dlo.y, dlo.z, dlo.w, dhi.x, dhi.y, dhi.z, dhi.w};
    const float* pf = prefix + ((size_t)(b * NCHUNK + c)) * D_DIM + d8 * 8;
    float p[8];
#pragma unroll
    for (int j = 0; j < 8; ++j) p[j] = pf[j];
    u16* up = u + ((size_t)b * T_LEN + (size_t)c * CHUNK) * D_DIM + d8 * 8;
    for (int s = 0; s < CHUNK; ++s) {
        u16x8 v = *(const u16x8*)(up + (size_t)s * D_DIM);
        u16x8 o;
#pragma unroll
        for (int j = 0; j < 8; ++j) {
            p[j] = fmaf(p[j], dec[j], bf2f(v[j]));
            o[j] = f2bf(p[j]);
        }
        *(u16x8*)(up + (size_t)s * D_DIM) = o;
    }
}

extern "C" void kernel_launch(void* const* d_in, const int* in_sizes, int n_in,
                              void* d_out, int out_size, void* d_ws, size_t ws_size,
                              hipStream_t stream) {
    const float* x       = (const float*)d_in[0];
    const float* state_p = (const float*)d_in[1];
    const float* decay   = (const float*)d_in[2];
    const float* mass    = (const float*)d_in[3];
    const float* Wq      = (const float*)d_in[4];
    const float* bq      = (const float*)d_in[5];
    const float* Wk      = (const float*)d_in[6];
    const float* bk      = (const float*)d_in[7];
    const float* Wv      = (const float*)d_in[8];
    const float* bv      = (const float*)d_in[9];

    float* out     = (float*)d_out;
    float* final_p = out + (size_t)M_ROWS * D_DIM;

    // x_bf16 staged in d_out's first 64MB (dead before final GEMM overwrites it)
    u16* xb = (u16*)d_out;

    // workspace layout (~74MB)
    u16* wcat = (u16*)d_ws;                          // [2048][1024] interleaved Wk/Wv
    u16* wqb  = wcat + 2048 * 1024;
    u16* ub   = wqb + 1024 * 1024;                   // u then p in place, 64MB
    float* localc = (float*)(ub + (size_t)M_ROWS * D_DIM);
    float* prefix = localc + B_SZ * NCHUNK * D_DIM;

    convert_all_kernel<<<4096, 256, 0, stream>>>(x, Wk, Wv, Wq, xb, wcat, wqb);

    // u = sigmoid(x Wk^T + bk) * (x Wv^T + bv); also emits localc (fused carry)
    gemm18_kernel<true><<<dim3(1024), dim3(512), 0, stream>>>(
        xb, wcat, bk, bv, ub, nullptr, decay, localc);

    carry_scan_kernel<<<512, 1024, 0, stream>>>(localc, state_p, decay, prefix, final_p);
    reconstruct_kernel<<<256, 256, 0, stream>>>(ub, decay, prefix);

    // velocities = (p Wq^T + bq) / mass
    gemm18_kernel<false><<<dim3(512), dim3(512), 0, stream>>>(
        ub, wqb, bq, mass, nullptr, out, nullptr, nullptr);
}

// Round 20
// 291.417 us; speedup vs baseline: 1.0102x; 1.0022x over previous
//
#include <hip/hip_runtime.h>
#include <stdint.h>
#include <stddef.h>

#define D_DIM 1024
#define T_LEN 4096
#define B_SZ 8
#define M_ROWS 32768   // B_SZ * T_LEN
#define KTOT 1024
#define CHUNK 64
#define NCHUNK 64      // T_LEN / CHUNK

typedef unsigned short u16;
typedef unsigned short u16x8 __attribute__((ext_vector_type(8)));
typedef __bf16 bf16x8 __attribute__((ext_vector_type(8)));
typedef float f32x4 __attribute__((ext_vector_type(4)));

__device__ __forceinline__ u16 f2bf(float f) {
    union { float f; unsigned u; } v; v.f = f;
    unsigned r = v.u + 0x7fffu + ((v.u >> 16) & 1u);
    return (u16)(r >> 16);
}
__device__ __forceinline__ float bf2f(u16 h) {
    union { unsigned u; float f; } v; v.u = ((unsigned)h) << 16;
    return v.f;
}

// ---------------- fused f32->bf16 conversion: x + {Wk,Wv->wcat, Wq->wqb} ----
__global__ void convert_all_kernel(const float* __restrict__ x,
                                   const float* __restrict__ Wk, const float* __restrict__ Wv,
                                   const float* __restrict__ Wq,
                                   u16* __restrict__ xb, u16* __restrict__ wcat,
                                   u16* __restrict__ wqb) {
    const int NX = (M_ROWS * D_DIM) / 4;          // x in float4 units
    const int total = NX + 3072 * 256;            // + 3072 weight rows x 256 float4
    int stride = gridDim.x * blockDim.x;
    for (int j = blockIdx.x * blockDim.x + threadIdx.x; j < total; j += stride) {
        const float4* s4;
        ushort4* d4;
        if (j < NX) {
            s4 = (const float4*)x + j;
            d4 = (ushort4*)xb + j;
        } else {
            int idx = j - NX;
            int r = idx >> 8, c4 = idx & 255;
            if (r < 2048) {
                int g = r >> 5, jj = r & 31;
                s4 = (const float4*)((jj < 16 ? Wk : Wv) + (size_t)(g * 16 + (jj & 15)) * D_DIM) + c4;
                d4 = (ushort4*)(wcat + (size_t)r * D_DIM) + c4;
            } else {
                s4 = (const float4*)(Wq + (size_t)(r - 2048) * D_DIM) + c4;
                d4 = (ushort4*)(wqb + (size_t)(r - 2048) * D_DIM) + c4;
            }
        }
        float4 v = *s4;
        ushort4 o;
        o.x = f2bf(v.x); o.y = f2bf(v.y); o.z = f2bf(v.z); o.w = f2bf(v.w);
        *d4 = o;
    }
}

// ---------------- async global->LDS, 16B per lane ----------------
__device__ __forceinline__ void gload16(const u16* g, u16* l) {
    __builtin_amdgcn_global_load_lds(
        (const __attribute__((address_space(1))) void*)g,
        (__attribute__((address_space(3))) void*)l,
        16, 0, 0);
}

// ---------------- best-measured GEMM (r17 structure, no setprio) ------------
// K-loop: BM=BN=256, BK=64, 8 waves (2Mx4N), wave 128x64, LDS 2x64KB dbuf,
// 4 phases/K-tile, compiler-scheduled lgkm, counted vmcnt(2)+barrier at p1/p3.
// CAT epilogue: u-tile -> XOR-swizzled LDS, coalesced u16x8 stores + fused
// per-chunk carry. Single epilogue: direct stores (measured best).
template<bool CAT>
__global__ __launch_bounds__(512, 2) void gemm18_kernel(
    const u16* __restrict__ A,
    const u16* __restrict__ Bg,
    const float* __restrict__ bias0,
    const float* __restrict__ bias1,
    u16* __restrict__ Uout,
    float* __restrict__ Fout,
    const float* __restrict__ decay,
    float* __restrict__ localc)
{
    constexpr int NT = KTOT / 64;      // 16 K-tiles
    __shared__ u16 smem[2 * 32768];    // 128 KB

    const int tid  = threadIdx.x;
    const int w    = tid >> 6;
    const int lane = tid & 63;

    const int cpx = gridDim.x >> 3;
    const int swz = (blockIdx.x & 7) * cpx + (blockIdx.x >> 3);
    const int nCol = CAT ? 8 : 4;
    const int M0 = (swz / nCol) * 256;
    const int N0 = (swz % nCol) * 256;

    const int srow = lane >> 2;
    const int sg   = (lane & 3) ^ ((srow >> 1) & 3);

    const u16* pA0 = A  + (size_t)(M0 + w * 32 +      srow) * KTOT + sg * 8;
    const u16* pA1 = A  + (size_t)(M0 + w * 32 + 16 + srow) * KTOT + sg * 8;
    const u16* pB0 = Bg + (size_t)(N0 + w * 32 +      srow) * KTOT + sg * 8;
    const u16* pB1 = Bg + (size_t)(N0 + w * 32 + 16 + srow) * KTOT + sg * 8;

    auto stA = [&](u16* nxt, int h) {
        gload16(pA0, nxt + h * 8192 + w * 1024);       pA0 += 32;
        gload16(pA1, nxt + h * 8192 + w * 1024 + 512); pA1 += 32;
    };
    auto stB = [&](u16* nxt, int h) {
        gload16(pB0, nxt + 16384 + h * 8192 + w * 1024);       pB0 += 32;
        gload16(pB1, nxt + 16384 + h * 8192 + w * 1024 + 512); pB1 += 32;
    };

    const int wrow = (w >> 2) * 128;
    const int wcol = (w & 3) * 64;
    const int fr = lane & 15;
    const int fq = lane >> 4;

    int offA[8], offB[4];
#pragma unroll
    for (int m = 0; m < 8; ++m) {
        int row = wrow + m * 16 + fr;
        offA[m] = row * 32 + ((fq ^ ((row >> 1) & 3)) << 3);
    }
#pragma unroll
    for (int n = 0; n < 4; ++n) {
        int row = wcol + n * 16 + fr;
        offB[n] = 16384 + row * 32 + ((fq ^ ((row >> 1) & 3)) << 3);
    }

    f32x4 acc[8][4] = {};
    bf16x8 aA[4], aB[4], aC[4], aD[4], bA[4], bC[4];

    stA(smem, 0); stB(smem, 0); stA(smem, 1); stB(smem, 1);
    asm volatile("s_waitcnt vmcnt(4)" ::: "memory");
    __builtin_amdgcn_s_barrier();
#pragma unroll
    for (int m = 0; m < 4; ++m) aA[m] = *(const bf16x8*)(smem + offA[m]);
#pragma unroll
    for (int n = 0; n < 4; ++n) bA[n] = *(const bf16x8*)(smem + offB[n]);

#pragma unroll 1
    for (int t = 0; t < NT; ++t) {
        const u16* cur = smem + (t & 1) * 32768;
        u16* nxt = smem + ((t + 1) & 1) * 32768;
        const bool pf = (t + 1 < NT);

        // ===== p0: read aB + stage A-ks0(t+1) + MFMA Q0 =====
#pragma unroll
        for (int m = 0; m < 4; ++m) aB[m] = *(const bf16x8*)(cur + offA[4 + m]);
        if (pf) stA(nxt, 0);
#pragma unroll
        for (int m = 0; m < 4; ++m)
#pragma unroll
            for (int n = 0; n < 4; ++n)
                acc[m][n] = __builtin_amdgcn_mfma_f32_16x16x32_bf16(aA[m], bA[n], acc[m][n], 0, 0, 0);

        // ===== p1: vmcnt(2) retires tile-t ks1; BAR; read aC,bC + stage + MFMA Q1 =====
        if (pf) { asm volatile("s_waitcnt vmcnt(2)" ::: "memory"); }
        else    { asm volatile("s_waitcnt vmcnt(0)" ::: "memory"); }
        __builtin_amdgcn_s_barrier();
#pragma unroll
        for (int m = 0; m < 4; ++m) aC[m] = *(const bf16x8*)(cur + 8192 + offA[m]);
#pragma unroll
        for (int n = 0; n < 4; ++n) bC[n] = *(const bf16x8*)(cur + 8192 + offB[n]);
        if (pf) stB(nxt, 0);
#pragma unroll
        for (int m = 0; m < 4; ++m)
#pragma unroll
            for (int n = 0; n < 4; ++n)
                acc[4 + m][n] = __builtin_amdgcn_mfma_f32_16x16x32_bf16(aB[m], bA[n], acc[4 + m][n], 0, 0, 0);

        // ===== p2: read aD + stage A-ks1(t+1) + MFMA Q2 =====
#pragma unroll
        for (int m = 0; m < 4; ++m) aD[m] = *(const bf16x8*)(cur + 8192 + offA[4 + m]);
        if (pf) stA(nxt, 1);
#pragma unroll
        for (int m = 0; m < 4; ++m)
#pragma unroll
            for (int n = 0; n < 4; ++n)
                acc[m][n] = __builtin_amdgcn_mfma_f32_16x16x32_bf16(aC[m], bC[n], acc[m][n], 0, 0, 0);

        // ===== p3: vmcnt(2) retires tile-(t+1) ks0; BAR; read next aA,bA + stage + MFMA Q3 =====
        if (pf) { asm volatile("s_waitcnt vmcnt(2)" ::: "memory"); }
        __builtin_amdgcn_s_barrier();
        if (pf) {
#pragma unroll
            for (int m = 0; m < 4; ++m) aA[m] = *(const bf16x8*)(nxt + offA[m]);
#pragma unroll
            for (int n = 0; n < 4; ++n) bA[n] = *(const bf16x8*)(nxt + offB[n]);
            stB(nxt, 1);
        }
#pragma unroll
        for (int m = 0; m < 4; ++m)
#pragma unroll
            for (int n = 0; n < 4; ++n)
                acc[4 + m][n] = __builtin_amdgcn_mfma_f32_16x16x32_bf16(aD[m], bC[n], acc[4 + m][n], 0, 0, 0);
    }

    // epilogue (C/D layout: col=lane&15, row=(lane>>4)*4+reg)
    if (CAT) {
        asm volatile("s_waitcnt lgkmcnt(0) vmcnt(0)" ::: "memory");
        __syncthreads();   // all waves done; smem free
        u16 (*uld)[128] = (u16(*)[128])smem;
        const int ucol0 = N0 / 2;
#pragma unroll
        for (int m = 0; m < 8; ++m) {
#pragma unroll
            for (int p = 0; p < 2; ++p) {
                int lcol = (w & 3) * 32 + p * 16 + fr;
                float b0 = bias0[ucol0 + lcol];
                float b1 = bias1[ucol0 + lcol];
#pragma unroll
                for (int j = 0; j < 4; ++j) {
                    int row = wrow + m * 16 + fq * 4 + j;
                    float kl = acc[m][2 * p][j] + b0;
                    float vv = acc[m][2 * p + 1][j] + b1;
                    float sig = 1.0f / (1.0f + __expf(-kl));
                    uld[row][lcol ^ (((row >> 2) & 3) << 4)] = f2bf(sig * vv);
                }
            }
        }
        __syncthreads();
#pragma unroll
        for (int g = 0; g < 8; ++g) {
            int idx = tid + g * 512;
            int row = idx >> 4, grp = idx & 15;
            int lcol = (grp * 8) ^ (((row >> 2) & 3) << 4);
            *(u16x8*)(Uout + (size_t)(M0 + row) * D_DIM + ucol0 + grp * 8) =
                *(const u16x8*)&uld[row][lcol];
        }
        {
            int chunk = tid >> 7;
            int col   = tid & 127;
            float dec = decay[ucol0 + col];
            float carry = 0.f;
#pragma unroll 4
            for (int s = 0; s < 64; ++s) {
                int r = chunk * 64 + s;
                carry = fmaf(carry, dec, bf2f(uld[r][col ^ (((r >> 2) & 3) << 4)]));
            }
            localc[(size_t)(M0 / 64 + chunk) * D_DIM + ucol0 + col] = carry;
        }
    } else {
#pragma unroll
        for (int n = 0; n < 4; ++n) {
            int col = N0 + wcol + n * 16 + fr;
            float b0 = bias0[col];
            float b1 = bias1[col];
#pragma unroll
            for (int m = 0; m < 8; ++m) {
                int row0 = M0 + wrow + m * 16 + fq * 4;
#pragma unroll
                for (int j = 0; j < 4; ++j)
                    Fout[(size_t)(row0 + j) * D_DIM + col] = (acc[m][n][j] + b0) / b1;
            }
        }
    }
}

// ---------------- scan pass B: PARALLEL pair-scan over chunk carries --------
__global__ __launch_bounds__(1024) void carry_scan_kernel(
    const float* __restrict__ localc, const float* __restrict__ state_p,
    const float* __restrict__ decay, float* __restrict__ prefix,
    float* __restrict__ final_p)
{
    __shared__ float Vs[64][17], Gs[64][17];
    const int tid = threadIdx.x;
    const int c  = tid >> 4;
    const int dl = tid & 15;
    const int b  = blockIdx.x >> 6;    // 8 batches
    const int dg = blockIdx.x & 63;    // 64 d-groups of 16
    const int d  = dg * 16 + dl;

    float dec = decay[d];
    float g = dec;
#pragma unroll
    for (int i = 0; i < 6; ++i) g *= g;     // dec^64
    float v = localc[(size_t)(b * NCHUNK + c) * D_DIM + d];
    Vs[c][dl] = v; Gs[c][dl] = g;
    __syncthreads();
#pragma unroll
    for (int s = 1; s < 64; s <<= 1) {
        float lv = 0.f, lg = 1.f;
        if (c >= s) { lv = Vs[c - s][dl]; lg = Gs[c - s][dl]; }
        __syncthreads();
        if (c >= s) {
            float sv = Vs[c][dl], sgg = Gs[c][dl];
            Vs[c][dl] = fmaf(lv, sgg, sv);
            Gs[c][dl] = lg * sgg;
        }
        __syncthreads();
    }
    float P0 = state_p[b * D_DIM + d];
    float pref = (c == 0) ? P0 : fmaf(P0, Gs[c - 1][dl], Vs[c - 1][dl]);
    prefix[(size_t)(b * NCHUNK + c) * D_DIM + d] = pref;
    if (c == 63)
        final_p[b * D_DIM + d] = fmaf(P0, Gs[63][dl], Vs[63][dl]);
}

// ---------------- scan pass C: reconstruct p in place (x8 vectorized) ----------------
__global__ void reconstruct_kernel(u16* __restrict__ u, const float* __restrict__ decay,
                                   const float* __restrict__ prefix) {
    int id = blockIdx.x * blockDim.x + threadIdx.x;   // 65536
    int d8 = id & 127;
    int c  = (id >> 7) & (NCHUNK - 1);
    int b  = id >> 13;
    float4 dlo = ((const float4*)decay)[d8 * 2];
    float4 dhi = ((const float4*)decay)[d8 * 2 + 1];
    float dec[8] = {dlo.x, dlo.y, dlo.z, dlo.w, dhi.x, dhi.y, dhi.z, dhi.w};
    const float* pf = prefix + ((size_t)(b * NCHUNK + c)) * D_DIM + d8 * 8;
    float p[8];
#pragma unroll
    for (int j = 0; j < 8; ++j) p[j] = pf[j];
    u16* up = u + ((size_t)b * T_LEN + (size_t)c * CHUNK) * D_DIM + d8 * 8;
    for (int s = 0; s < CHUNK; ++s) {
        u16x8 v = *(const u16x8*)(up + (size_t)s * D_DIM);
        u16x8 o;
#pragma unroll
        for (int j = 0; j < 8; ++j) {
            p[j] = fmaf(p[j], dec[j], bf2f(v[j]));
            o[j] = f2bf(p[j]);
        }
        *(u16x8*)(up + (size_t)s * D_DIM) = o;
    }
}

extern "C" void kernel_launch(void* const* d_in, const int* in_sizes, int n_in,
                              void* d_out, int out_size, void* d_ws, size_t ws_size,
                              hipStream_t stream) {
    const float* x       = (const float*)d_in[0];
    const float* state_p = (const float*)d_in[1];
    const float* decay   = (const float*)d_in[2];
    const float* mass    = (const float*)d_in[3];
    const float* Wq      = (const float*)d_in[4];
    const float* bq      = (const float*)d_in[5];
    const float* Wk      = (const float*)d_in[6];
    const float* bk      = (const float*)d_in[7];
    const float* Wv      = (const float*)d_in[8];
    const float* bv      = (const float*)d_in[9];

    float* out     = (float*)d_out;
    float* final_p = out + (size_t)M_ROWS * D_DIM;

    // x_bf16 staged in d_out's first 64MB (dead before final GEMM overwrites it)
    u16* xb = (u16*)d_out;

    // workspace layout (~74MB)
    u16* wcat = (u16*)d_ws;                          // [2048][1024] interleaved Wk/Wv
    u16* wqb  = wcat + 2048 * 1024;
    u16* ub   = wqb + 1024 * 1024;                   // u then p in place, 64MB
    float* localc = (float*)(ub + (size_t)M_ROWS * D_DIM);
    float* prefix = localc + B_SZ * NCHUNK * D_DIM;

    convert_all_kernel<<<4096, 256, 0, stream>>>(x, Wk, Wv, Wq, xb, wcat, wqb);

    // u = sigmoid(x Wk^T + bk) * (x Wv^T + bv); also emits localc (fused carry)
    gemm18_kernel<true><<<dim3(1024), dim3(512), 0, stream>>>(
        xb, wcat, bk, bv, ub, nullptr, decay, localc);

    carry_scan_kernel<<<512, 1024, 0, stream>>>(localc, state_p, decay, prefix, final_p);
    reconstruct_kernel<<<256, 256, 0, stream>>>(ub, decay, prefix);

    // velocities = (p Wq^T + bq) / mass
    gemm18_kernel<false><<<dim3(512), dim3(512), 0, stream>>>(
        ub, wqb, bq, mass, nullptr, out, nullptr, nullptr);
}